// Round 1
// baseline (359.646 us; speedup 1.0000x reference)
//
#include <hip/hip_runtime.h>
#include <cstdint>

#define N_NODES 100000
#define E_EDGES 1600000
#define IN_F 128
#define OUT_F 64
#define NEG_SLOPE 0.2f
#define CAP 64

// ---------------------------------------------------------------------------
// Kernel A: h_lin = h @ W^T  (+ fused s_src = h_lin@a1, s_dst = h_lin@a2)
// One wave per row; lane = output feature f. W[f][:] lives in 128 VGPRs per
// lane; h row is wave-uniform -> scalar loads (readfirstlane forces SGPR).
// ---------------------------------------------------------------------------
__global__ __launch_bounds__(256) void k_linear(
    const float* __restrict__ h, const float* __restrict__ W,
    const float* __restrict__ a, float* __restrict__ h_lin,
    float* __restrict__ s_src, float* __restrict__ s_dst) {
  const int lane = threadIdx.x & 63;
  const int wid  = (blockIdx.x * blockDim.x + threadIdx.x) >> 6;
  const int nw   = (gridDim.x * blockDim.x) >> 6;

  // Per-lane copy of W row f (128 floats = 32 VGPR-quads). Read once.
  float wreg[IN_F];
  const float4* w4 = (const float4*)(W + (size_t)lane * IN_F);
#pragma unroll
  for (int i = 0; i < IN_F / 4; ++i) {
    float4 t = w4[i];
    wreg[4 * i + 0] = t.x; wreg[4 * i + 1] = t.y;
    wreg[4 * i + 2] = t.z; wreg[4 * i + 3] = t.w;
  }
  const float a1 = a[lane];
  const float a2 = a[OUT_F + lane];

  for (int row = wid; row < N_NODES; row += nw) {
    const int urow = __builtin_amdgcn_readfirstlane(row);
    const float* hrow = h + (size_t)urow * IN_F;
    float acc = 0.f;
#pragma unroll
    for (int k = 0; k < IN_F; ++k) acc = fmaf(hrow[k], wreg[k], acc);
    h_lin[(size_t)urow * OUT_F + lane] = acc;

    // wave-reduce s_src / s_dst contributions
    float p = acc * a1;
    float q = acc * a2;
#pragma unroll
    for (int off = 32; off; off >>= 1) {
      p += __shfl_xor(p, off, 64);
      q += __shfl_xor(q, off, 64);
    }
    if (lane == 0) { s_src[urow] = p; s_dst[urow] = q; }
  }
}

// ---------------------------------------------------------------------------
// Kernel B: bucket-CSR build. For each edge (incl. N self-loops appended),
// idx = atomicAdd(cnt[r]); colb[r*CAP + idx] = c.  Poisson(16) degrees =>
// P(deg>=CAP) ~ 1e-18/node; clamp only as a memory-safety guard.
// ---------------------------------------------------------------------------
__global__ __launch_bounds__(256) void k_scatter(
    const int* __restrict__ ei, int* __restrict__ cnt, int* __restrict__ colb) {
  const int e = blockIdx.x * blockDim.x + threadIdx.x;
  const int total = E_EDGES + N_NODES;
  if (e >= total) return;
  int r, c;
  if (e < E_EDGES) { r = ei[e]; c = ei[E_EDGES + e]; }
  else             { r = e - E_EDGES; c = r; }
  const int idx = atomicAdd(&cnt[r], 1);
  if (idx < CAP) colb[(size_t)r * CAP + idx] = c;
}

// ---------------------------------------------------------------------------
// Kernel C: per-node softmax-weighted aggregation + ELU.
// One wave per node; lane = feature. Edge columns & s_dst gathered
// lane-parallel, exp once per edge; j-loop broadcasts via shfl with 4x
// unroll so 4 independent h_lin gather loads are in flight.
// ---------------------------------------------------------------------------
__global__ __launch_bounds__(256) void k_aggregate(
    const float* __restrict__ h_lin, const float* __restrict__ s_src,
    const float* __restrict__ s_dst, const int* __restrict__ cnt,
    const int* __restrict__ colb, float* __restrict__ out) {
  const int lane = threadIdx.x & 63;
  const int wid  = (blockIdx.x * blockDim.x + threadIdx.x) >> 6;
  const int nw   = (gridDim.x * blockDim.x) >> 6;

  for (int n = wid; n < N_NODES; n += nw) {
    const int un  = __builtin_amdgcn_readfirstlane(n);
    const int deg = min(cnt[un], CAP);
    const float s1 = s_src[un];

    // lane-parallel: lane j holds edge j's column + exp(e_j)
    int c = 0;
    if (lane < deg) c = colb[(size_t)un * CAP + lane];
    float e = s1 + ((lane < deg) ? s_dst[c] : 0.f);
    e = e > 0.f ? e : NEG_SLOPE * e;
    const float ex = __expf(e);

    float acc = 0.f, dsum = 0.f;
    int j = 0;
    for (; j + 4 <= deg; j += 4) {
      const int   c0 = __shfl(c, j, 64),      c1 = __shfl(c, j + 1, 64);
      const int   c2 = __shfl(c, j + 2, 64),  c3 = __shfl(c, j + 3, 64);
      const float e0 = __shfl(ex, j, 64),     e1 = __shfl(ex, j + 1, 64);
      const float e2 = __shfl(ex, j + 2, 64), e3 = __shfl(ex, j + 3, 64);
      const float v0 = h_lin[(size_t)c0 * OUT_F + lane];
      const float v1 = h_lin[(size_t)c1 * OUT_F + lane];
      const float v2 = h_lin[(size_t)c2 * OUT_F + lane];
      const float v3 = h_lin[(size_t)c3 * OUT_F + lane];
      acc = fmaf(e0, v0, acc); acc = fmaf(e1, v1, acc);
      acc = fmaf(e2, v2, acc); acc = fmaf(e3, v3, acc);
      dsum += (e0 + e1) + (e2 + e3);
    }
    for (; j < deg; ++j) {
      const int   cj = __shfl(c, j, 64);
      const float ej = __shfl(ex, j, 64);
      acc = fmaf(ej, h_lin[(size_t)cj * OUT_F + lane], acc);
      dsum += ej;
    }

    const float hp = acc / dsum;
    out[(size_t)un * OUT_F + lane] = hp > 0.f ? hp : __expf(hp) - 1.f;
  }
}

// ---------------------------------------------------------------------------
extern "C" void kernel_launch(void* const* d_in, const int* in_sizes, int n_in,
                              void* d_out, int out_size, void* d_ws, size_t ws_size,
                              hipStream_t stream) {
  const float* h  = (const float*)d_in[0];
  const float* W  = (const float*)d_in[1];
  const float* a  = (const float*)d_in[2];
  const int*   ei = (const int*)d_in[3];
  float* out = (float*)d_out;

  // workspace layout
  float* h_lin = (float*)d_ws;                  // N*64
  float* s_src = h_lin + (size_t)N_NODES * OUT_F;  // N
  float* s_dst = s_src + N_NODES;               // N
  int*   cnt   = (int*)(s_dst + N_NODES);       // N
  int*   colb  = cnt + N_NODES;                 // N*CAP

  hipMemsetAsync(cnt, 0, (size_t)N_NODES * sizeof(int), stream);

  k_linear<<<768, 256, 0, stream>>>(h, W, a, h_lin, s_src, s_dst);

  k_scatter<<<(E_EDGES + N_NODES + 255) / 256, 256, 0, stream>>>(ei, cnt, colb);

  // one wave per node: 100000 waves = 25000 blocks of 256
  k_aggregate<<<25000, 256, 0, stream>>>(h_lin, s_src, s_dst, cnt, colb, out);
}

// Round 2
// 356.121 us; speedup vs baseline: 1.0099x; 1.0099x over previous
//
#include <hip/hip_runtime.h>
#include <cstdint>

#define N_NODES 100000
#define E_EDGES 1600000
#define IN_F 128
#define OUT_F 64
#define NEG_SLOPE 0.2f

// binning config
#define NB 2048          // coarse buckets
#define RPB 49           // rows per bucket (2048*49 = 100352 >= N)
#define SUBS 4           // sub-cursors per bucket (atomic contention /4)
#define SUBCAP 384       // records per sub-region; E[208] + 12 sigma
#define LCAP 64          // per-row column capacity (Poisson(16)+1, P(>=64)~1e-18)

// ---------------------------------------------------------------------------
// Kernel A: h_lin = h @ W^T (+ fused s_src = h_lin@a1, s_dst = h_lin@a2)
// One wave per row; lane = output feature. W row in VGPRs, h row via scalar
// path (wave-uniform index -> s_load).
// ---------------------------------------------------------------------------
__global__ __launch_bounds__(256) void k_linear(
    const float* __restrict__ h, const float* __restrict__ W,
    const float* __restrict__ a, float* __restrict__ h_lin,
    float* __restrict__ s_src, float* __restrict__ s_dst) {
  const int lane = threadIdx.x & 63;
  const int wid  = (blockIdx.x * blockDim.x + threadIdx.x) >> 6;
  const int nw   = (gridDim.x * blockDim.x) >> 6;

  float wreg[IN_F];
  const float4* w4 = (const float4*)(W + (size_t)lane * IN_F);
#pragma unroll
  for (int i = 0; i < IN_F / 4; ++i) {
    float4 t = w4[i];
    wreg[4 * i + 0] = t.x; wreg[4 * i + 1] = t.y;
    wreg[4 * i + 2] = t.z; wreg[4 * i + 3] = t.w;
  }
  const float a1 = a[lane];
  const float a2 = a[OUT_F + lane];

  for (int row = wid; row < N_NODES; row += nw) {
    const int urow = __builtin_amdgcn_readfirstlane(row);
    const float* hrow = h + (size_t)urow * IN_F;
    float acc = 0.f;
#pragma unroll
    for (int k = 0; k < IN_F; ++k) acc = fmaf(hrow[k], wreg[k], acc);
    h_lin[(size_t)urow * OUT_F + lane] = acc;

    float p = acc * a1;
    float q = acc * a2;
#pragma unroll
    for (int off = 32; off; off >>= 1) {
      p += __shfl_xor(p, off, 64);
      q += __shfl_xor(q, off, 64);
    }
    if (lane == 0) { s_src[urow] = p; s_dst[urow] = q; }
  }
}

// ---------------------------------------------------------------------------
// Kernel B: coarse binning. Append (r,c) records into bucket r/RPB via one of
// SUBS atomic sub-cursors. Append-allocation => consecutive stores share cache
// lines => near-streaming writebacks (vs 15x amplification of direct CSR
// scatter).
// ---------------------------------------------------------------------------
__global__ __launch_bounds__(256) void k_bin(
    const int* __restrict__ ei, int* __restrict__ cursor,
    int2* __restrict__ regions) {
  const int e = blockIdx.x * blockDim.x + threadIdx.x;
  const int total = E_EDGES + N_NODES;
  if (e >= total) return;
  int r, c;
  if (e < E_EDGES) { r = ei[e]; c = ei[E_EDGES + e]; }
  else             { r = e - E_EDGES; c = r; }
  const unsigned b = (unsigned)r / RPB;          // const div -> magic mul
  const int s = (threadIdx.x >> 2) & (SUBS - 1); // spread self-loop runs too
  const int cur = b * SUBS + s;
  const int pos = atomicAdd(&cursor[cur], 1);
  if (pos < SUBCAP) regions[(size_t)cur * SUBCAP + pos] = make_int2(r, c);
}

// ---------------------------------------------------------------------------
// Kernel C (fused): per-bucket LDS CSR build + softmax aggregation + ELU.
// One workgroup (4 waves) per bucket of 49 rows. 12.7 KB LDS -> 8 wg/CU.
// ---------------------------------------------------------------------------
__global__ __launch_bounds__(256) void k_agg(
    const float* __restrict__ h_lin, const float* __restrict__ s_src,
    const float* __restrict__ s_dst, const int* __restrict__ cursor,
    const int2* __restrict__ regions, float* __restrict__ out) {
  __shared__ int lcnt[RPB];
  __shared__ int lcol[RPB * LCAP];
  const int b    = blockIdx.x;
  const int tid  = threadIdx.x;
  const int row0 = b * RPB;

  for (int i = tid; i < RPB; i += 256) lcnt[i] = 0;
  __syncthreads();

  // build per-row CSR in LDS from this bucket's sub-regions
#pragma unroll
  for (int s = 0; s < SUBS; ++s) {
    const int cur = b * SUBS + s;
    const int m = min(cursor[cur], SUBCAP);
    const int2* reg = regions + (size_t)cur * SUBCAP;
    for (int i = tid; i < m; i += 256) {
      const int2 rc = reg[i];
      const int rl = rc.x - row0;
      const int slot = atomicAdd(&lcnt[rl], 1);
      if (slot < LCAP) lcol[rl * LCAP + slot] = rc.y;
    }
  }
  __syncthreads();

  const int lane = tid & 63;
  const int w    = tid >> 6;
  for (int rl = w; rl < RPB; rl += 4) {
    const int row = row0 + rl;
    if (row >= N_NODES) break;
    const int deg = min(lcnt[rl], LCAP);
    const float s1 = s_src[row];

    // lane j holds edge j's column and exp(e_j)
    int c = 0;
    if (lane < deg) c = lcol[rl * LCAP + lane];
    float e = s1 + ((lane < deg) ? s_dst[c] : 0.f);
    e = e > 0.f ? e : NEG_SLOPE * e;
    const float ex = __expf(e);

    float acc = 0.f, dsum = 0.f;
    int j = 0;
    for (; j + 4 <= deg; j += 4) {
      const int   c0 = __shfl(c, j, 64),      c1 = __shfl(c, j + 1, 64);
      const int   c2 = __shfl(c, j + 2, 64),  c3 = __shfl(c, j + 3, 64);
      const float e0 = __shfl(ex, j, 64),     e1 = __shfl(ex, j + 1, 64);
      const float e2 = __shfl(ex, j + 2, 64), e3 = __shfl(ex, j + 3, 64);
      const float v0 = h_lin[(size_t)c0 * OUT_F + lane];
      const float v1 = h_lin[(size_t)c1 * OUT_F + lane];
      const float v2 = h_lin[(size_t)c2 * OUT_F + lane];
      const float v3 = h_lin[(size_t)c3 * OUT_F + lane];
      acc = fmaf(e0, v0, acc); acc = fmaf(e1, v1, acc);
      acc = fmaf(e2, v2, acc); acc = fmaf(e3, v3, acc);
      dsum += (e0 + e1) + (e2 + e3);
    }
    for (; j < deg; ++j) {
      const int   cj = __shfl(c, j, 64);
      const float ej = __shfl(ex, j, 64);
      acc = fmaf(ej, h_lin[(size_t)cj * OUT_F + lane], acc);
      dsum += ej;
    }

    const float hp = acc / dsum;
    out[(size_t)row * OUT_F + lane] = hp > 0.f ? hp : __expf(hp) - 1.f;
  }
}

// ---------------------------------------------------------------------------
extern "C" void kernel_launch(void* const* d_in, const int* in_sizes, int n_in,
                              void* d_out, int out_size, void* d_ws, size_t ws_size,
                              hipStream_t stream) {
  const float* h  = (const float*)d_in[0];
  const float* W  = (const float*)d_in[1];
  const float* a  = (const float*)d_in[2];
  const int*   ei = (const int*)d_in[3];
  float* out = (float*)d_out;

  // workspace layout (51.6 MB total)
  float* h_lin = (float*)d_ws;                         // N*64 floats
  float* s_src = h_lin + (size_t)N_NODES * OUT_F;      // N
  float* s_dst = s_src + N_NODES;                      // N
  int*   cursor = (int*)(s_dst + N_NODES);             // NB*SUBS ints
  int2*  regions = (int2*)(cursor + NB * SUBS);        // NB*SUBS*SUBCAP int2

  hipMemsetAsync(cursor, 0, (size_t)NB * SUBS * sizeof(int), stream);

  k_linear<<<768, 256, 0, stream>>>(h, W, a, h_lin, s_src, s_dst);

  k_bin<<<(E_EDGES + N_NODES + 255) / 256, 256, 0, stream>>>(ei, cursor, regions);

  k_agg<<<NB, 256, 0, stream>>>(h_lin, s_src, s_dst, cursor, regions, out);
}

// Round 3
// 271.911 us; speedup vs baseline: 1.3227x; 1.3097x over previous
//
#include <hip/hip_runtime.h>
#include <cstdint>

#define N_NODES 100000
#define E_EDGES 1600000
#define TOTAL_E (E_EDGES + N_NODES)
#define IN_F 128
#define OUT_F 64
#define NEG_SLOPE 0.2f

#define NB   256     // coarse buckets
#define RPB  391     // rows per bucket: ceil(100000/256)
#define GCAP 8192    // per-bucket record capacity (mean 6647, +19 sigma)
#define TILE 4096    // edges per k_bin tile
#define EPT  (TILE / 256)

// ---------------------------------------------------------------------------
// Kernel A: h_lin = h @ W^T (+ fused s_src = h_lin@a1, s_dst = h_lin@a2)
// ---------------------------------------------------------------------------
__global__ __launch_bounds__(256) void k_linear(
    const float* __restrict__ h, const float* __restrict__ W,
    const float* __restrict__ a, float* __restrict__ h_lin,
    float* __restrict__ s_src, float* __restrict__ s_dst) {
  const int lane = threadIdx.x & 63;
  const int wid  = (blockIdx.x * blockDim.x + threadIdx.x) >> 6;
  const int nw   = (gridDim.x * blockDim.x) >> 6;

  float wreg[IN_F];
  const float4* w4 = (const float4*)(W + (size_t)lane * IN_F);
#pragma unroll
  for (int i = 0; i < IN_F / 4; ++i) {
    float4 t = w4[i];
    wreg[4 * i + 0] = t.x; wreg[4 * i + 1] = t.y;
    wreg[4 * i + 2] = t.z; wreg[4 * i + 3] = t.w;
  }
  const float a1 = a[lane];
  const float a2 = a[OUT_F + lane];

  for (int row = wid; row < N_NODES; row += nw) {
    const int urow = __builtin_amdgcn_readfirstlane(row);
    const float* hrow = h + (size_t)urow * IN_F;
    float acc = 0.f;
#pragma unroll
    for (int k = 0; k < IN_F; ++k) acc = fmaf(hrow[k], wreg[k], acc);
    h_lin[(size_t)urow * OUT_F + lane] = acc;

    float p = acc * a1;
    float q = acc * a2;
#pragma unroll
    for (int off = 32; off; off >>= 1) {
      p += __shfl_xor(p, off, 64);
      q += __shfl_xor(q, off, 64);
    }
    if (lane == 0) { s_src[urow] = p; s_dst[urow] = q; }
  }
}

// ---------------------------------------------------------------------------
// Kernel B: LDS-staged partition into NB coarse buckets.
// Tile -> LDS histogram -> block scan -> LDS reorder -> one global atomic per
// (bucket,tile) -> lane-coalesced contiguous run writes (full cache lines
// written by one wave => no cross-XCD partial-line writebacks).
// Record: 4 B packed = (r % RPB) << 17 | c   (rl<512, c<131072)
// ---------------------------------------------------------------------------
__global__ __launch_bounds__(256) void k_bin(
    const int* __restrict__ ei, int* __restrict__ gcur,
    unsigned* __restrict__ regions) {
  __shared__ unsigned reord[TILE];          // 16 KB
  __shared__ unsigned char bktid[TILE];     // 4 KB
  __shared__ int hist[NB];                  // 1 KB
  __shared__ int scan_s[NB];                // 1 KB (exclusive scan)
  __shared__ int adj[NB];                   // 1 KB (cursor, then gbase-scan)
  __shared__ int wsum[4];

  const int tid = threadIdx.x;
  const int e0  = blockIdx.x * TILE;

  hist[tid] = 0;
  __syncthreads();

  int      myb[EPT];
  unsigned myrec[EPT];
#pragma unroll
  for (int k = 0; k < EPT; ++k) {
    const int e = e0 + k * 256 + tid;
    int b = -1; unsigned rec = 0;
    if (e < TOTAL_E) {
      int r, c;
      if (e < E_EDGES) { r = ei[e]; c = ei[E_EDGES + e]; }
      else             { r = e - E_EDGES; c = r; }
      b = (int)((unsigned)r / RPB);
      rec = ((unsigned)(r - b * RPB) << 17) | (unsigned)c;
      atomicAdd(&hist[b], 1);
    }
    myb[k] = b; myrec[k] = rec;
  }
  __syncthreads();

  // exclusive scan over NB=256 entries (one per thread)
  const int lane = tid & 63, w = tid >> 6;
  {
    const int v = hist[tid];
    int incl = v;
#pragma unroll
    for (int o = 1; o < 64; o <<= 1) {
      const int t = __shfl_up(incl, o, 64);
      if (lane >= o) incl += t;
    }
    if (lane == 63) wsum[w] = incl;
    __syncthreads();
    int wpre = 0;
    for (int i = 0; i < w; ++i) wpre += wsum[i];
    scan_s[tid] = wpre + incl - v;
    adj[tid]    = wpre + incl - v;   // scatter cursor
  }
  __syncthreads();

  // reorder into LDS by bucket
#pragma unroll
  for (int k = 0; k < EPT; ++k) {
    if (myb[k] >= 0) {
      const int pos = atomicAdd(&adj[myb[k]], 1);
      reord[pos]  = myrec[k];
      bktid[pos]  = (unsigned char)myb[k];
    }
  }
  __syncthreads();

  // claim global ranges; adj[b] := gbase - scan_s[b]
  {
    const int cnt = hist[tid];
    int a2 = 0;
    if (cnt > 0) a2 = atomicAdd(&gcur[tid], cnt) - scan_s[tid];
    __syncthreads();
    adj[tid] = a2;
  }
  __syncthreads();

  // lane-coalesced run write-out
  const int tilesz = scan_s[NB - 1] + hist[NB - 1];
  for (int i = tid; i < tilesz; i += 256) {
    const int b    = bktid[i];
    const int slot = adj[b] + i;          // position within bucket region
    if (slot < GCAP) regions[(size_t)b * GCAP + slot] = reord[i];
  }
}

// ---------------------------------------------------------------------------
// Kernel C: one 1024-thread WG per coarse bucket. Coalesced record read ->
// exact per-row CSR in LDS (hist/scan/scatter) -> per-row lane-parallel
// softmax aggregation + ELU.
// ---------------------------------------------------------------------------
__global__ __launch_bounds__(1024) void k_agg(
    const float* __restrict__ h_lin, const float* __restrict__ s_src,
    const float* __restrict__ s_dst, const int* __restrict__ gcur,
    const unsigned* __restrict__ regions, float* __restrict__ out) {
  __shared__ int cnt[RPB];        // per-row degree
  __shared__ int off[RPB];        // exclusive scan; post-scatter = end offset
  __shared__ int cols[GCAP];      // 32 KB CSR column storage
  __shared__ int wsum8[8];

  const int b    = blockIdx.x;
  const int tid  = threadIdx.x;
  const int row0 = b * RPB;
  const int m    = min(gcur[b], GCAP);
  const unsigned* reg = regions + (size_t)b * GCAP;

  for (int i = tid; i < RPB; i += 1024) cnt[i] = 0;
  __syncthreads();

  // phase 1: coalesced read + LDS histogram; records kept in registers
  unsigned myrec[GCAP / 1024];
  int nmy = 0;
  for (int i = tid; i < m; i += 1024) {
    const unsigned rec = reg[i];
    myrec[nmy++] = rec;
    atomicAdd(&cnt[rec >> 17], 1);
  }
  __syncthreads();

  // phase 2: exclusive scan of cnt[0..RPB) using first 512 threads
  const int lane = tid & 63, wv = tid >> 6;
  int incl = 0, v = 0;
  if (tid < 512) {
    v = (tid < RPB) ? cnt[tid] : 0;
    incl = v;
#pragma unroll
    for (int o = 1; o < 64; o <<= 1) {
      const int t = __shfl_up(incl, o, 64);
      if (lane >= o) incl += t;
    }
    if (lane == 63) wsum8[wv] = incl;
  }
  __syncthreads();
  if (tid < RPB) {
    int wpre = 0;
    for (int i = 0; i < wv; ++i) wpre += wsum8[i];
    off[tid] = wpre + incl - v;
  }
  __syncthreads();

  // phase 3: scatter into LDS CSR (off becomes end offset)
  for (int k = 0; k < nmy; ++k) {
    const unsigned rec = myrec[k];
    const int rl  = rec >> 17;
    const int pos = atomicAdd(&off[rl], 1);
    cols[pos] = (int)(rec & 0x1FFFFu);
  }
  __syncthreads();

  // phase 4: per-row softmax aggregation, one wave per row (16 waves)
  for (int rl = wv; rl < RPB; rl += 16) {
    const int row = row0 + rl;
    if (row >= N_NODES) break;
    const int dcnt  = cnt[rl];
    const int end   = off[rl];
    const int start = end - dcnt;
    const int deg   = min(dcnt, 64);   // P(deg>64) ~ 1e-18; memory-safety cap
    const float s1 = s_src[row];

    int c = 0;
    if (lane < deg) c = cols[start + lane];
    float e = s1 + ((lane < deg) ? s_dst[c] : 0.f);
    e = e > 0.f ? e : NEG_SLOPE * e;
    const float ex = __expf(e);

    float acc = 0.f, dsum = 0.f;
    int j = 0;
    for (; j + 4 <= deg; j += 4) {
      const int   c0 = __shfl(c, j, 64),      c1 = __shfl(c, j + 1, 64);
      const int   c2 = __shfl(c, j + 2, 64),  c3 = __shfl(c, j + 3, 64);
      const float e0 = __shfl(ex, j, 64),     e1 = __shfl(ex, j + 1, 64);
      const float e2 = __shfl(ex, j + 2, 64), e3 = __shfl(ex, j + 3, 64);
      const float v0 = h_lin[(size_t)c0 * OUT_F + lane];
      const float v1 = h_lin[(size_t)c1 * OUT_F + lane];
      const float v2 = h_lin[(size_t)c2 * OUT_F + lane];
      const float v3 = h_lin[(size_t)c3 * OUT_F + lane];
      acc = fmaf(e0, v0, acc); acc = fmaf(e1, v1, acc);
      acc = fmaf(e2, v2, acc); acc = fmaf(e3, v3, acc);
      dsum += (e0 + e1) + (e2 + e3);
    }
    for (; j < deg; ++j) {
      const int   cj = __shfl(c, j, 64);
      const float ej = __shfl(ex, j, 64);
      acc = fmaf(ej, h_lin[(size_t)cj * OUT_F + lane], acc);
      dsum += ej;
    }

    const float hp = acc / dsum;
    out[(size_t)row * OUT_F + lane] = hp > 0.f ? hp : __expf(hp) - 1.f;
  }
}

// ---------------------------------------------------------------------------
extern "C" void kernel_launch(void* const* d_in, const int* in_sizes, int n_in,
                              void* d_out, int out_size, void* d_ws, size_t ws_size,
                              hipStream_t stream) {
  const float* h  = (const float*)d_in[0];
  const float* W  = (const float*)d_in[1];
  const float* a  = (const float*)d_in[2];
  const int*   ei = (const int*)d_in[3];
  float* out = (float*)d_out;

  // workspace layout
  float*    h_lin   = (float*)d_ws;                        // N*64 floats
  float*    s_src   = h_lin + (size_t)N_NODES * OUT_F;     // N
  float*    s_dst   = s_src + N_NODES;                     // N
  int*      gcur    = (int*)(s_dst + N_NODES);             // NB ints
  unsigned* regions = (unsigned*)(gcur + NB);              // NB*GCAP u32 (8.4 MB)

  hipMemsetAsync(gcur, 0, NB * sizeof(int), stream);

  k_linear<<<768, 256, 0, stream>>>(h, W, a, h_lin, s_src, s_dst);

  k_bin<<<(TOTAL_E + TILE - 1) / TILE, 256, 0, stream>>>(ei, gcur, regions);

  k_agg<<<NB, 1024, 0, stream>>>(h_lin, s_src, s_dst, gcur, regions, out);
}

// Round 4
// 216.062 us; speedup vs baseline: 1.6646x; 1.2585x over previous
//
#include <hip/hip_runtime.h>
#include <cstdint>

#define N_NODES 100000
#define E_EDGES 1600000
#define TOTAL_E (E_EDGES + N_NODES)
#define IN_F 128
#define OUT_F 64
#define NEG_SLOPE 0.2f

#define NB   256     // coarse buckets
#define RPB  391     // rows per bucket: ceil(100000/256)
#define GCAP 8192    // per-bucket record capacity (mean 6647, +19 sigma)
#define TILE 4096    // edges per k_bin tile
#define EPT  (TILE / 256)

typedef __attribute__((ext_vector_type(8))) short short8;   // 8 bf16 = 4 VGPR
typedef __attribute__((ext_vector_type(4))) float float4v;  // MFMA C/D

__device__ __forceinline__ short bf16_rne(float x) {
  unsigned u = __builtin_bit_cast(unsigned, x);
  unsigned r = u + 0x7FFFu + ((u >> 16) & 1u);
  return (short)(r >> 16);
}
__device__ __forceinline__ float bf16_f(short s) {
  unsigned u = ((unsigned)(unsigned short)s) << 16;
  return __builtin_bit_cast(float, u);
}

// ---------------------------------------------------------------------------
// Kernel A (MFMA): h_lin = h @ W^T via split-bf16 (hi/lo), fused s_src/s_dst.
// One wave per 16-row tile; 4 n-tiles of mfma_f32_16x16x32_bf16.
// W converted once per block into LDS in fragment-linear layout:
// element W[n][k] -> frag f=(k>>5)*4+(n>>4), lane=((k>>3)&3)*16+(n&15), j=k&7
// so each B-fragment read is lane*16B contiguous ds_read_b128 (conflict-free).
// ---------------------------------------------------------------------------
__global__ __launch_bounds__(256) void k_linear(
    const float* __restrict__ h, const float* __restrict__ W,
    const float* __restrict__ a, float* __restrict__ h_lin,
    float* __restrict__ s_src, float* __restrict__ s_dst) {
  __shared__ alignas(16) short Whi[16 * 512];   // 16 KB
  __shared__ alignas(16) short Wlo[16 * 512];   // 16 KB

  const int tid = threadIdx.x;
  // convert W (64x128 fp32) -> hi/lo bf16 fragments in LDS
  for (int i = tid; i < OUT_F * IN_F; i += 256) {
    const int n = i >> 7, k = i & 127;
    const float x = W[i];
    const short hi = bf16_rne(x);
    const short lo = bf16_rne(x - bf16_f(hi));
    const int idx = (((k >> 5) * 4 + (n >> 4)) << 9) |
                    (((((k >> 3) & 3) << 4) | (n & 15)) << 3) | (k & 7);
    Whi[idx] = hi;
    Wlo[idx] = lo;
  }
  __syncthreads();

  const int lane = tid & 63;
  const int m    = lane & 15;   // C col / A row-in-tile
  const int q    = lane >> 4;   // quad: k-block selector
  const int wgid = blockIdx.x * 4 + (tid >> 6);
  const int nw   = gridDim.x * 4;

  // per-lane attention coefficients for the fused s_src/s_dst
  float a1v[4], a2v[4];
#pragma unroll
  for (int t = 0; t < 4; ++t) {
    a1v[t] = a[t * 16 + m];
    a2v[t] = a[OUT_F + t * 16 + m];
  }

  for (int tile = wgid; tile < N_NODES / 16; tile += nw) {
    const int row0 = tile * 16;
    float4v acc[4] = {{0.f,0.f,0.f,0.f},{0.f,0.f,0.f,0.f},
                      {0.f,0.f,0.f,0.f},{0.f,0.f,0.f,0.f}};

    const float* hbase = h + (size_t)(row0 + m) * IN_F + q * 8;
#pragma unroll
    for (int ks = 0; ks < 4; ++ks) {           // k0 = 32*ks
      const float4 f0 = *(const float4*)(hbase + 32 * ks);
      const float4 f1 = *(const float4*)(hbase + 32 * ks + 4);
      float av[8] = {f0.x, f0.y, f0.z, f0.w, f1.x, f1.y, f1.z, f1.w};
      short8 ahi, alo;
#pragma unroll
      for (int j = 0; j < 8; ++j) {
        const short hi = bf16_rne(av[j]);
        ahi[j] = hi;
        alo[j] = bf16_rne(av[j] - bf16_f(hi));
      }
#pragma unroll
      for (int t = 0; t < 4; ++t) {
        const int fb = ((ks * 4 + t) << 9) + lane * 8;
        const short8 bhi = *(const short8*)&Whi[fb];
        const short8 blo = *(const short8*)&Wlo[fb];
        acc[t] = __builtin_amdgcn_mfma_f32_16x16x32_bf16(ahi, bhi, acc[t], 0, 0, 0);
        acc[t] = __builtin_amdgcn_mfma_f32_16x16x32_bf16(ahi, blo, acc[t], 0, 0, 0);
        acc[t] = __builtin_amdgcn_mfma_f32_16x16x32_bf16(alo, bhi, acc[t], 0, 0, 0);
      }
    }

    // store h_lin: C/D layout col=lane&15, row=q*4+r
#pragma unroll
    for (int t = 0; t < 4; ++t)
#pragma unroll
      for (int r = 0; r < 4; ++r)
        h_lin[(size_t)(row0 + q * 4 + r) * OUT_F + t * 16 + m] = acc[t][r];

    // fused s_src/s_dst: reduce over the 16 column-lanes per row
#pragma unroll
    for (int r = 0; r < 4; ++r) {
      float p = acc[0][r] * a1v[0] + acc[1][r] * a1v[1] +
                acc[2][r] * a1v[2] + acc[3][r] * a1v[3];
      float qq = acc[0][r] * a2v[0] + acc[1][r] * a2v[1] +
                 acc[2][r] * a2v[2] + acc[3][r] * a2v[3];
#pragma unroll
      for (int o = 1; o < 16; o <<= 1) {
        p  += __shfl_xor(p, o, 64);
        qq += __shfl_xor(qq, o, 64);
      }
      if (m == 0) {
        s_src[row0 + q * 4 + r] = p;
        s_dst[row0 + q * 4 + r] = qq;
      }
    }
  }
}

// ---------------------------------------------------------------------------
// Kernel B: LDS-staged partition into NB coarse buckets (unchanged).
// ---------------------------------------------------------------------------
__global__ __launch_bounds__(256) void k_bin(
    const int* __restrict__ ei, int* __restrict__ gcur,
    unsigned* __restrict__ regions) {
  __shared__ unsigned reord[TILE];
  __shared__ unsigned char bktid[TILE];
  __shared__ int hist[NB];
  __shared__ int scan_s[NB];
  __shared__ int adj[NB];
  __shared__ int wsum[4];

  const int tid = threadIdx.x;
  const int e0  = blockIdx.x * TILE;

  hist[tid] = 0;
  __syncthreads();

  int      myb[EPT];
  unsigned myrec[EPT];
#pragma unroll
  for (int k = 0; k < EPT; ++k) {
    const int e = e0 + k * 256 + tid;
    int b = -1; unsigned rec = 0;
    if (e < TOTAL_E) {
      int r, c;
      if (e < E_EDGES) { r = ei[e]; c = ei[E_EDGES + e]; }
      else             { r = e - E_EDGES; c = r; }
      b = (int)((unsigned)r / RPB);
      rec = ((unsigned)(r - b * RPB) << 17) | (unsigned)c;
      atomicAdd(&hist[b], 1);
    }
    myb[k] = b; myrec[k] = rec;
  }
  __syncthreads();

  const int lane = tid & 63, w = tid >> 6;
  {
    const int v = hist[tid];
    int incl = v;
#pragma unroll
    for (int o = 1; o < 64; o <<= 1) {
      const int t = __shfl_up(incl, o, 64);
      if (lane >= o) incl += t;
    }
    if (lane == 63) wsum[w] = incl;
    __syncthreads();
    int wpre = 0;
    for (int i = 0; i < w; ++i) wpre += wsum[i];
    scan_s[tid] = wpre + incl - v;
    adj[tid]    = wpre + incl - v;
  }
  __syncthreads();

#pragma unroll
  for (int k = 0; k < EPT; ++k) {
    if (myb[k] >= 0) {
      const int pos = atomicAdd(&adj[myb[k]], 1);
      reord[pos]  = myrec[k];
      bktid[pos]  = (unsigned char)myb[k];
    }
  }
  __syncthreads();

  {
    const int cnt = hist[tid];
    int a2 = 0;
    if (cnt > 0) a2 = atomicAdd(&gcur[tid], cnt) - scan_s[tid];
    __syncthreads();
    adj[tid] = a2;
  }
  __syncthreads();

  const int tilesz = scan_s[NB - 1] + hist[NB - 1];
  for (int i = tid; i < tilesz; i += 256) {
    const int b    = bktid[i];
    const int slot = adj[b] + i;
    if (slot < GCAP) regions[(size_t)b * GCAP + slot] = reord[i];
  }
}

// ---------------------------------------------------------------------------
// Kernel C: per-bucket LDS CSR + softmax aggregation + ELU (unchanged).
// ---------------------------------------------------------------------------
__global__ __launch_bounds__(1024) void k_agg(
    const float* __restrict__ h_lin, const float* __restrict__ s_src,
    const float* __restrict__ s_dst, const int* __restrict__ gcur,
    const unsigned* __restrict__ regions, float* __restrict__ out) {
  __shared__ int cnt[RPB];
  __shared__ int off[RPB];
  __shared__ int cols[GCAP];
  __shared__ int wsum8[8];

  const int b    = blockIdx.x;
  const int tid  = threadIdx.x;
  const int row0 = b * RPB;
  const int m    = min(gcur[b], GCAP);
  const unsigned* reg = regions + (size_t)b * GCAP;

  for (int i = tid; i < RPB; i += 1024) cnt[i] = 0;
  __syncthreads();

  unsigned myrec[GCAP / 1024];
  int nmy = 0;
  for (int i = tid; i < m; i += 1024) {
    const unsigned rec = reg[i];
    myrec[nmy++] = rec;
    atomicAdd(&cnt[rec >> 17], 1);
  }
  __syncthreads();

  const int lane = tid & 63, wv = tid >> 6;
  int incl = 0, v = 0;
  if (tid < 512) {
    v = (tid < RPB) ? cnt[tid] : 0;
    incl = v;
#pragma unroll
    for (int o = 1; o < 64; o <<= 1) {
      const int t = __shfl_up(incl, o, 64);
      if (lane >= o) incl += t;
    }
    if (lane == 63) wsum8[wv] = incl;
  }
  __syncthreads();
  if (tid < RPB) {
    int wpre = 0;
    for (int i = 0; i < wv; ++i) wpre += wsum8[i];
    off[tid] = wpre + incl - v;
  }
  __syncthreads();

  for (int k = 0; k < nmy; ++k) {
    const unsigned rec = myrec[k];
    const int rl  = rec >> 17;
    const int pos = atomicAdd(&off[rl], 1);
    cols[pos] = (int)(rec & 0x1FFFFu);
  }
  __syncthreads();

  for (int rl = wv; rl < RPB; rl += 16) {
    const int row = row0 + rl;
    if (row >= N_NODES) break;
    const int dcnt  = cnt[rl];
    const int end   = off[rl];
    const int start = end - dcnt;
    const int deg   = min(dcnt, 64);
    const float s1 = s_src[row];

    int c = 0;
    if (lane < deg) c = cols[start + lane];
    float e = s1 + ((lane < deg) ? s_dst[c] : 0.f);
    e = e > 0.f ? e : NEG_SLOPE * e;
    const float ex = __expf(e);

    float acc = 0.f, dsum = 0.f;
    int j = 0;
    for (; j + 4 <= deg; j += 4) {
      const int   c0 = __shfl(c, j, 64),      c1 = __shfl(c, j + 1, 64);
      const int   c2 = __shfl(c, j + 2, 64),  c3 = __shfl(c, j + 3, 64);
      const float e0 = __shfl(ex, j, 64),     e1 = __shfl(ex, j + 1, 64);
      const float e2 = __shfl(ex, j + 2, 64), e3 = __shfl(ex, j + 3, 64);
      const float v0 = h_lin[(size_t)c0 * OUT_F + lane];
      const float v1 = h_lin[(size_t)c1 * OUT_F + lane];
      const float v2 = h_lin[(size_t)c2 * OUT_F + lane];
      const float v3 = h_lin[(size_t)c3 * OUT_F + lane];
      acc = fmaf(e0, v0, acc); acc = fmaf(e1, v1, acc);
      acc = fmaf(e2, v2, acc); acc = fmaf(e3, v3, acc);
      dsum += (e0 + e1) + (e2 + e3);
    }
    for (; j < deg; ++j) {
      const int   cj = __shfl(c, j, 64);
      const float ej = __shfl(ex, j, 64);
      acc = fmaf(ej, h_lin[(size_t)cj * OUT_F + lane], acc);
      dsum += ej;
    }

    const float hp = acc / dsum;
    out[(size_t)row * OUT_F + lane] = hp > 0.f ? hp : __expf(hp) - 1.f;
  }
}

// ---------------------------------------------------------------------------
extern "C" void kernel_launch(void* const* d_in, const int* in_sizes, int n_in,
                              void* d_out, int out_size, void* d_ws, size_t ws_size,
                              hipStream_t stream) {
  const float* h  = (const float*)d_in[0];
  const float* W  = (const float*)d_in[1];
  const float* a  = (const float*)d_in[2];
  const int*   ei = (const int*)d_in[3];
  float* out = (float*)d_out;

  float*    h_lin   = (float*)d_ws;
  float*    s_src   = h_lin + (size_t)N_NODES * OUT_F;
  float*    s_dst   = s_src + N_NODES;
  int*      gcur    = (int*)(s_dst + N_NODES);
  unsigned* regions = (unsigned*)(gcur + NB);

  hipMemsetAsync(gcur, 0, NB * sizeof(int), stream);

  // 782 blocks = 3128 waves -> ~2 row-tiles per wave (6250 tiles total)
  k_linear<<<782, 256, 0, stream>>>(h, W, a, h_lin, s_src, s_dst);

  k_bin<<<(TOTAL_E + TILE - 1) / TILE, 256, 0, stream>>>(ei, gcur, regions);

  k_agg<<<NB, 1024, 0, stream>>>(h_lin, s_src, s_dst, gcur, regions, out);
}

// Round 7
// 204.389 us; speedup vs baseline: 1.7596x; 1.0571x over previous
//
#include <hip/hip_runtime.h>
#include <cstdint>

#define N_NODES 100000
#define E_EDGES 1600000
#define TOTAL_E (E_EDGES + N_NODES)
#define IN_F 128
#define OUT_F 64
#define NEG_SLOPE 0.2f

#define NB   256     // coarse buckets (round-4 proven)
#define RPB  391     // rows per bucket: ceil(100000/256)
#define GCAP 8192    // per-bucket record capacity
#define TILE 4096    // edges per k_bin tile
#define EPT  (TILE / 256)
#define HALF_R 196   // rows in half 0 (half 1 gets RPB-196 = 195)
#define CCAP 4608    // per-half CSR capacity (mean 3332, +22 sigma)

typedef __attribute__((ext_vector_type(8))) short short8;
typedef __attribute__((ext_vector_type(4))) float float4v;

__device__ __forceinline__ short bf16_rne(float x) {
  unsigned u = __builtin_bit_cast(unsigned, x);
  unsigned r = u + 0x7FFFu + ((u >> 16) & 1u);
  return (short)(r >> 16);
}
__device__ __forceinline__ float bf16_f(short s) {
  unsigned u = ((unsigned)(unsigned short)s) << 16;
  return __builtin_bit_cast(float, u);
}

// ---------------------------------------------------------------------------
// Kernel A (MFMA): h_lin(fp32) = h @ W^T via split-bf16, fused s_src/s_dst.
// BYTE-IDENTICAL to round-4 version (passed, absmax 0.0078).
// ---------------------------------------------------------------------------
__global__ __launch_bounds__(256) void k_linear(
    const float* __restrict__ h, const float* __restrict__ W,
    const float* __restrict__ a, float* __restrict__ h_lin,
    float* __restrict__ s_src, float* __restrict__ s_dst) {
  __shared__ alignas(16) short Whi[16 * 512];
  __shared__ alignas(16) short Wlo[16 * 512];

  const int tid = threadIdx.x;
  for (int i = tid; i < OUT_F * IN_F; i += 256) {
    const int n = i >> 7, k = i & 127;
    const float x = W[i];
    const short hi = bf16_rne(x);
    const short lo = bf16_rne(x - bf16_f(hi));
    const int idx = (((k >> 5) * 4 + (n >> 4)) << 9) |
                    (((((k >> 3) & 3) << 4) | (n & 15)) << 3) | (k & 7);
    Whi[idx] = hi;
    Wlo[idx] = lo;
  }
  __syncthreads();

  const int lane = tid & 63;
  const int m    = lane & 15;
  const int q    = lane >> 4;
  const int wgid = blockIdx.x * 4 + (tid >> 6);
  const int nw   = gridDim.x * 4;

  float a1v[4], a2v[4];
#pragma unroll
  for (int t = 0; t < 4; ++t) {
    a1v[t] = a[t * 16 + m];
    a2v[t] = a[OUT_F + t * 16 + m];
  }

  for (int tile = wgid; tile < N_NODES / 16; tile += nw) {
    const int row0 = tile * 16;
    float4v acc[4] = {{0.f,0.f,0.f,0.f},{0.f,0.f,0.f,0.f},
                      {0.f,0.f,0.f,0.f},{0.f,0.f,0.f,0.f}};

    const float* hbase = h + (size_t)(row0 + m) * IN_F + q * 8;
#pragma unroll
    for (int ks = 0; ks < 4; ++ks) {
      const float4 f0 = *(const float4*)(hbase + 32 * ks);
      const float4 f1 = *(const float4*)(hbase + 32 * ks + 4);
      float av[8] = {f0.x, f0.y, f0.z, f0.w, f1.x, f1.y, f1.z, f1.w};
      short8 ahi, alo;
#pragma unroll
      for (int j = 0; j < 8; ++j) {
        const short hi = bf16_rne(av[j]);
        ahi[j] = hi;
        alo[j] = bf16_rne(av[j] - bf16_f(hi));
      }
#pragma unroll
      for (int t = 0; t < 4; ++t) {
        const int fb = ((ks * 4 + t) << 9) + lane * 8;
        const short8 bhi = *(const short8*)&Whi[fb];
        const short8 blo = *(const short8*)&Wlo[fb];
        acc[t] = __builtin_amdgcn_mfma_f32_16x16x32_bf16(ahi, bhi, acc[t], 0, 0, 0);
        acc[t] = __builtin_amdgcn_mfma_f32_16x16x32_bf16(ahi, blo, acc[t], 0, 0, 0);
        acc[t] = __builtin_amdgcn_mfma_f32_16x16x32_bf16(alo, bhi, acc[t], 0, 0, 0);
      }
    }

#pragma unroll
    for (int t = 0; t < 4; ++t)
#pragma unroll
      for (int r = 0; r < 4; ++r)
        h_lin[(size_t)(row0 + q * 4 + r) * OUT_F + t * 16 + m] = acc[t][r];

#pragma unroll
    for (int r = 0; r < 4; ++r) {
      float p = acc[0][r] * a1v[0] + acc[1][r] * a1v[1] +
                acc[2][r] * a1v[2] + acc[3][r] * a1v[3];
      float qq = acc[0][r] * a2v[0] + acc[1][r] * a2v[1] +
                 acc[2][r] * a2v[2] + acc[3][r] * a2v[3];
#pragma unroll
      for (int o = 1; o < 16; o <<= 1) {
        p  += __shfl_xor(p, o, 64);
        qq += __shfl_xor(qq, o, 64);
      }
      if (m == 0) {
        s_src[row0 + q * 4 + r] = p;
        s_dst[row0 + q * 4 + r] = qq;
      }
    }
  }
}

// ---------------------------------------------------------------------------
// Kernel B: LDS-staged partition into NB=256 coarse buckets.
// BYTE-IDENTICAL to round-4 version (passed).
// ---------------------------------------------------------------------------
__global__ __launch_bounds__(256) void k_bin(
    const int* __restrict__ ei, int* __restrict__ gcur,
    unsigned* __restrict__ regions) {
  __shared__ unsigned reord[TILE];
  __shared__ unsigned char bktid[TILE];
  __shared__ int hist[NB];
  __shared__ int scan_s[NB];
  __shared__ int adj[NB];
  __shared__ int wsum[4];

  const int tid = threadIdx.x;
  const int e0  = blockIdx.x * TILE;

  hist[tid] = 0;
  __syncthreads();

  int      myb[EPT];
  unsigned myrec[EPT];
#pragma unroll
  for (int k = 0; k < EPT; ++k) {
    const int e = e0 + k * 256 + tid;
    int b = -1; unsigned rec = 0;
    if (e < TOTAL_E) {
      int r, c;
      if (e < E_EDGES) { r = ei[e]; c = ei[E_EDGES + e]; }
      else             { r = e - E_EDGES; c = r; }
      b = (int)((unsigned)r / RPB);
      rec = ((unsigned)(r - b * RPB) << 17) | (unsigned)c;
      atomicAdd(&hist[b], 1);
    }
    myb[k] = b; myrec[k] = rec;
  }
  __syncthreads();

  const int lane = tid & 63, w = tid >> 6;
  {
    const int v = hist[tid];
    int incl = v;
#pragma unroll
    for (int o = 1; o < 64; o <<= 1) {
      const int t = __shfl_up(incl, o, 64);
      if (lane >= o) incl += t;
    }
    if (lane == 63) wsum[w] = incl;
    __syncthreads();
    int wpre = 0;
    for (int i = 0; i < w; ++i) wpre += wsum[i];
    scan_s[tid] = wpre + incl - v;
    adj[tid]    = wpre + incl - v;
  }
  __syncthreads();

#pragma unroll
  for (int k = 0; k < EPT; ++k) {
    if (myb[k] >= 0) {
      const int pos = atomicAdd(&adj[myb[k]], 1);
      reord[pos]  = myrec[k];
      bktid[pos]  = (unsigned char)myb[k];
    }
  }
  __syncthreads();

  {
    const int cnt = hist[tid];
    int a2 = 0;
    if (cnt > 0) a2 = atomicAdd(&gcur[tid], cnt) - scan_s[tid];
    __syncthreads();
    adj[tid] = a2;
  }
  __syncthreads();

  const int tilesz = scan_s[NB - 1] + hist[NB - 1];
  for (int i = tid; i < tilesz; i += 256) {
    const int b    = bktid[i];
    const int slot = adj[b] + i;
    if (slot < GCAP) regions[(size_t)b * GCAP + slot] = reord[i];
  }
}

// ---------------------------------------------------------------------------
// Kernel C: round-4 k_agg logic, split 2 blocks per bucket for occupancy.
// Block blk handles bucket blk>>1, row half blk&1 (196 / 195 rows).
// Each block reads all bucket records, keeps only its half. All per-edge
// arithmetic (CSR build, gather loop, dsum order, epilogue) = round 4.
// ---------------------------------------------------------------------------
__global__ __launch_bounds__(1024) void k_agg(
    const float* __restrict__ h_lin, const float* __restrict__ s_src,
    const float* __restrict__ s_dst, const int* __restrict__ gcur,
    const unsigned* __restrict__ regions, float* __restrict__ out) {
  __shared__ int cnt[HALF_R];
  __shared__ int off[HALF_R];
  __shared__ int cols[CCAP];       // 18 KB
  __shared__ int wsum4[4];

  const int blk  = blockIdx.x;
  const int b    = blk >> 1;
  const int half = blk & 1;
  const int rlo  = half * HALF_R;
  const int hr   = half ? (RPB - HALF_R) : HALF_R;   // 195 : 196
  const int tid  = threadIdx.x;
  const int row0 = b * RPB + rlo;
  const int m    = min(gcur[b], GCAP);
  const unsigned* reg = regions + (size_t)b * GCAP;

  for (int i = tid; i < HALF_R; i += 1024) cnt[i] = 0;
  __syncthreads();

  // phase 1: coalesced read of all bucket records; keep my half only
  unsigned myrec[GCAP / 1024];
  int nmy = 0;
  for (int i = tid; i < m; i += 1024) {
    const unsigned rec = reg[i];
    const int rl = (int)(rec >> 17) - rlo;
    if (rl >= 0 && rl < hr) {
      myrec[nmy++] = rec;
      atomicAdd(&cnt[rl], 1);
    }
  }
  __syncthreads();

  // phase 2: exclusive scan of cnt[0..hr) using first 4 waves
  const int lane = tid & 63, wv = tid >> 6;
  int incl = 0, v = 0;
  if (tid < 256) {
    v = (tid < hr) ? cnt[tid] : 0;
    incl = v;
#pragma unroll
    for (int o = 1; o < 64; o <<= 1) {
      const int t = __shfl_up(incl, o, 64);
      if (lane >= o) incl += t;
    }
    if (lane == 63) wsum4[wv] = incl;
  }
  __syncthreads();
  if (tid < hr) {
    int wpre = 0;
    for (int i = 0; i < wv; ++i) wpre += wsum4[i];
    off[tid] = wpre + incl - v;
  }
  __syncthreads();

  // phase 3: scatter my records into LDS CSR (off becomes end offset)
  for (int k = 0; k < nmy; ++k) {
    const unsigned rec = myrec[k];
    const int rl  = (int)(rec >> 17) - rlo;
    const int pos = atomicAdd(&off[rl], 1);
    if (pos < CCAP) cols[pos] = (int)(rec & 0x1FFFFu);
  }
  __syncthreads();

  // phase 4: per-row softmax aggregation, one wave per row (16 waves)
  for (int rl = wv; rl < hr; rl += 16) {
    const int row = row0 + rl;
    if (row >= N_NODES) break;
    const int dcnt  = cnt[rl];
    const int end   = off[rl];
    const int start = end - dcnt;
    const int deg   = min(dcnt, 64);
    const float s1 = s_src[row];

    int c = 0;
    if (lane < deg) c = cols[start + lane];
    float e = s1 + ((lane < deg) ? s_dst[c] : 0.f);
    e = e > 0.f ? e : NEG_SLOPE * e;
    const float ex = __expf(e);

    float acc = 0.f, dsum = 0.f;
    int j = 0;
    for (; j + 4 <= deg; j += 4) {
      const int   c0 = __shfl(c, j, 64),      c1 = __shfl(c, j + 1, 64);
      const int   c2 = __shfl(c, j + 2, 64),  c3 = __shfl(c, j + 3, 64);
      const float e0 = __shfl(ex, j, 64),     e1 = __shfl(ex, j + 1, 64);
      const float e2 = __shfl(ex, j + 2, 64), e3 = __shfl(ex, j + 3, 64);
      const float v0 = h_lin[(size_t)c0 * OUT_F + lane];
      const float v1 = h_lin[(size_t)c1 * OUT_F + lane];
      const float v2 = h_lin[(size_t)c2 * OUT_F + lane];
      const float v3 = h_lin[(size_t)c3 * OUT_F + lane];
      acc = fmaf(e0, v0, acc); acc = fmaf(e1, v1, acc);
      acc = fmaf(e2, v2, acc); acc = fmaf(e3, v3, acc);
      dsum += (e0 + e1) + (e2 + e3);
    }
    for (; j < deg; ++j) {
      const int   cj = __shfl(c, j, 64);
      const float ej = __shfl(ex, j, 64);
      acc = fmaf(ej, h_lin[(size_t)cj * OUT_F + lane], acc);
      dsum += ej;
    }

    const float hp = acc / dsum;
    out[(size_t)row * OUT_F + lane] = hp > 0.f ? hp : __expf(hp) - 1.f;
  }
}

// ---------------------------------------------------------------------------
extern "C" void kernel_launch(void* const* d_in, const int* in_sizes, int n_in,
                              void* d_out, int out_size, void* d_ws, size_t ws_size,
                              hipStream_t stream) {
  const float* h  = (const float*)d_in[0];
  const float* W  = (const float*)d_in[1];
  const float* a  = (const float*)d_in[2];
  const int*   ei = (const int*)d_in[3];
  float* out = (float*)d_out;

  float*    h_lin   = (float*)d_ws;
  float*    s_src   = h_lin + (size_t)N_NODES * OUT_F;
  float*    s_dst   = s_src + N_NODES;
  int*      gcur    = (int*)(s_dst + N_NODES);
  unsigned* regions = (unsigned*)(gcur + NB);

  hipMemsetAsync(gcur, 0, NB * sizeof(int), stream);

  k_linear<<<782, 256, 0, stream>>>(h, W, a, h_lin, s_src, s_dst);

  k_bin<<<(TOTAL_E + TILE - 1) / TILE, 256, 0, stream>>>(ei, gcur, regions);

  // 2 blocks per bucket -> 512 blocks = 2/CU = full 32 waves/CU
  k_agg<<<NB * 2, 1024, 0, stream>>>(h_lin, s_src, s_dst, gcur, regions, out);
}

// Round 8
// 189.808 us; speedup vs baseline: 1.8948x; 1.0768x over previous
//
#include <hip/hip_runtime.h>
#include <cstdint>

#define N_NODES 100000
#define E_EDGES 1600000
#define TOTAL_E (E_EDGES + N_NODES)
#define IN_F 128
#define OUT_F 64
#define NEG_SLOPE 0.2f

#define NB   256     // coarse buckets (round-4/7 proven)
#define RPB  391     // rows per bucket: ceil(100000/256)
#define GCAP 8192    // per-bucket record capacity
#define TILE 4096    // edges per k_bin tile
#define EPT  (TILE / 256)
#define HALF_R 196   // rows in half 0 (half 1 gets RPB-196 = 195)
#define CCAP 4608    // per-half CSR capacity (mean 3332, +22 sigma)

typedef __attribute__((ext_vector_type(8))) short short8;
typedef __attribute__((ext_vector_type(4))) float float4v;

__device__ __forceinline__ short bf16_rne(float x) {
  unsigned u = __builtin_bit_cast(unsigned, x);
  unsigned r = u + 0x7FFFu + ((u >> 16) & 1u);
  return (short)(r >> 16);
}
__device__ __forceinline__ float bf16_f(short s) {
  unsigned u = ((unsigned)(unsigned short)s) << 16;
  return __builtin_bit_cast(float, u);
}
__device__ __forceinline__ float bf16u_f(unsigned short s) {
  unsigned u = ((unsigned)s) << 16;
  return __builtin_bit_cast(float, u);
}

// ---------------------------------------------------------------------------
// Kernel A (MFMA): h_lin(bf16) = h @ W^T via split-bf16, fused s_src/s_dst.
// Identical to round-7 except the h_lin store is bf16 (RNE).
// ---------------------------------------------------------------------------
__global__ __launch_bounds__(256) void k_linear(
    const float* __restrict__ h, const float* __restrict__ W,
    const float* __restrict__ a, unsigned short* __restrict__ h_lin,
    float* __restrict__ s_src, float* __restrict__ s_dst) {
  __shared__ alignas(16) short Whi[16 * 512];
  __shared__ alignas(16) short Wlo[16 * 512];

  const int tid = threadIdx.x;
  for (int i = tid; i < OUT_F * IN_F; i += 256) {
    const int n = i >> 7, k = i & 127;
    const float x = W[i];
    const short hi = bf16_rne(x);
    const short lo = bf16_rne(x - bf16_f(hi));
    const int idx = (((k >> 5) * 4 + (n >> 4)) << 9) |
                    (((((k >> 3) & 3) << 4) | (n & 15)) << 3) | (k & 7);
    Whi[idx] = hi;
    Wlo[idx] = lo;
  }
  __syncthreads();

  const int lane = tid & 63;
  const int m    = lane & 15;
  const int q    = lane >> 4;
  const int wgid = blockIdx.x * 4 + (tid >> 6);
  const int nw   = gridDim.x * 4;

  float a1v[4], a2v[4];
#pragma unroll
  for (int t = 0; t < 4; ++t) {
    a1v[t] = a[t * 16 + m];
    a2v[t] = a[OUT_F + t * 16 + m];
  }

  for (int tile = wgid; tile < N_NODES / 16; tile += nw) {
    const int row0 = tile * 16;
    float4v acc[4] = {{0.f,0.f,0.f,0.f},{0.f,0.f,0.f,0.f},
                      {0.f,0.f,0.f,0.f},{0.f,0.f,0.f,0.f}};

    const float* hbase = h + (size_t)(row0 + m) * IN_F + q * 8;
#pragma unroll
    for (int ks = 0; ks < 4; ++ks) {
      const float4 f0 = *(const float4*)(hbase + 32 * ks);
      const float4 f1 = *(const float4*)(hbase + 32 * ks + 4);
      float av[8] = {f0.x, f0.y, f0.z, f0.w, f1.x, f1.y, f1.z, f1.w};
      short8 ahi, alo;
#pragma unroll
      for (int j = 0; j < 8; ++j) {
        const short hi = bf16_rne(av[j]);
        ahi[j] = hi;
        alo[j] = bf16_rne(av[j] - bf16_f(hi));
      }
#pragma unroll
      for (int t = 0; t < 4; ++t) {
        const int fb = ((ks * 4 + t) << 9) + lane * 8;
        const short8 bhi = *(const short8*)&Whi[fb];
        const short8 blo = *(const short8*)&Wlo[fb];
        acc[t] = __builtin_amdgcn_mfma_f32_16x16x32_bf16(ahi, bhi, acc[t], 0, 0, 0);
        acc[t] = __builtin_amdgcn_mfma_f32_16x16x32_bf16(ahi, blo, acc[t], 0, 0, 0);
        acc[t] = __builtin_amdgcn_mfma_f32_16x16x32_bf16(alo, bhi, acc[t], 0, 0, 0);
      }
    }

    // store h_lin in bf16: C/D layout col=lane&15, row=q*4+r
#pragma unroll
    for (int t = 0; t < 4; ++t)
#pragma unroll
      for (int r = 0; r < 4; ++r)
        h_lin[(size_t)(row0 + q * 4 + r) * OUT_F + t * 16 + m] =
            (unsigned short)bf16_rne(acc[t][r]);

#pragma unroll
    for (int r = 0; r < 4; ++r) {
      float p = acc[0][r] * a1v[0] + acc[1][r] * a1v[1] +
                acc[2][r] * a1v[2] + acc[3][r] * a1v[3];
      float qq = acc[0][r] * a2v[0] + acc[1][r] * a2v[1] +
                 acc[2][r] * a2v[2] + acc[3][r] * a2v[3];
#pragma unroll
      for (int o = 1; o < 16; o <<= 1) {
        p  += __shfl_xor(p, o, 64);
        qq += __shfl_xor(qq, o, 64);
      }
      if (m == 0) {
        s_src[row0 + q * 4 + r] = p;
        s_dst[row0 + q * 4 + r] = qq;
      }
    }
  }
}

// ---------------------------------------------------------------------------
// Kernel B: LDS-staged partition into NB=256 coarse buckets.
// BYTE-IDENTICAL to round-4/7 version (passed).
// ---------------------------------------------------------------------------
__global__ __launch_bounds__(256) void k_bin(
    const int* __restrict__ ei, int* __restrict__ gcur,
    unsigned* __restrict__ regions) {
  __shared__ unsigned reord[TILE];
  __shared__ unsigned char bktid[TILE];
  __shared__ int hist[NB];
  __shared__ int scan_s[NB];
  __shared__ int adj[NB];
  __shared__ int wsum[4];

  const int tid = threadIdx.x;
  const int e0  = blockIdx.x * TILE;

  hist[tid] = 0;
  __syncthreads();

  int      myb[EPT];
  unsigned myrec[EPT];
#pragma unroll
  for (int k = 0; k < EPT; ++k) {
    const int e = e0 + k * 256 + tid;
    int b = -1; unsigned rec = 0;
    if (e < TOTAL_E) {
      int r, c;
      if (e < E_EDGES) { r = ei[e]; c = ei[E_EDGES + e]; }
      else             { r = e - E_EDGES; c = r; }
      b = (int)((unsigned)r / RPB);
      rec = ((unsigned)(r - b * RPB) << 17) | (unsigned)c;
      atomicAdd(&hist[b], 1);
    }
    myb[k] = b; myrec[k] = rec;
  }
  __syncthreads();

  const int lane = tid & 63, w = tid >> 6;
  {
    const int v = hist[tid];
    int incl = v;
#pragma unroll
    for (int o = 1; o < 64; o <<= 1) {
      const int t = __shfl_up(incl, o, 64);
      if (lane >= o) incl += t;
    }
    if (lane == 63) wsum[w] = incl;
    __syncthreads();
    int wpre = 0;
    for (int i = 0; i < w; ++i) wpre += wsum[i];
    scan_s[tid] = wpre + incl - v;
    adj[tid]    = wpre + incl - v;
  }
  __syncthreads();

#pragma unroll
  for (int k = 0; k < EPT; ++k) {
    if (myb[k] >= 0) {
      const int pos = atomicAdd(&adj[myb[k]], 1);
      reord[pos]  = myrec[k];
      bktid[pos]  = (unsigned char)myb[k];
    }
  }
  __syncthreads();

  {
    const int cnt = hist[tid];
    int a2 = 0;
    if (cnt > 0) a2 = atomicAdd(&gcur[tid], cnt) - scan_s[tid];
    __syncthreads();
    adj[tid] = a2;
  }
  __syncthreads();

  const int tilesz = scan_s[NB - 1] + hist[NB - 1];
  for (int i = tid; i < tilesz; i += 256) {
    const int b    = bktid[i];
    const int slot = adj[b] + i;
    if (slot < GCAP) regions[(size_t)b * GCAP + slot] = reord[i];
  }
}

// ---------------------------------------------------------------------------
// Kernel C: round-7 k_agg (2 blocks/bucket, full occupancy). Only change:
// h_lin elements are bf16 (ushort load + shift to fp32).
// ---------------------------------------------------------------------------
__global__ __launch_bounds__(1024) void k_agg(
    const unsigned short* __restrict__ h_lin, const float* __restrict__ s_src,
    const float* __restrict__ s_dst, const int* __restrict__ gcur,
    const unsigned* __restrict__ regions, float* __restrict__ out) {
  __shared__ int cnt[HALF_R];
  __shared__ int off[HALF_R];
  __shared__ int cols[CCAP];       // 18 KB
  __shared__ int wsum4[4];

  const int blk  = blockIdx.x;
  const int b    = blk >> 1;
  const int half = blk & 1;
  const int rlo  = half * HALF_R;
  const int hr   = half ? (RPB - HALF_R) : HALF_R;   // 195 : 196
  const int tid  = threadIdx.x;
  const int row0 = b * RPB + rlo;
  const int m    = min(gcur[b], GCAP);
  const unsigned* reg = regions + (size_t)b * GCAP;

  for (int i = tid; i < HALF_R; i += 1024) cnt[i] = 0;
  __syncthreads();

  // phase 1: coalesced read of all bucket records; keep my half only
  unsigned myrec[GCAP / 1024];
  int nmy = 0;
  for (int i = tid; i < m; i += 1024) {
    const unsigned rec = reg[i];
    const int rl = (int)(rec >> 17) - rlo;
    if (rl >= 0 && rl < hr) {
      myrec[nmy++] = rec;
      atomicAdd(&cnt[rl], 1);
    }
  }
  __syncthreads();

  // phase 2: exclusive scan of cnt[0..hr) using first 4 waves
  const int lane = tid & 63, wv = tid >> 6;
  int incl = 0, v = 0;
  if (tid < 256) {
    v = (tid < hr) ? cnt[tid] : 0;
    incl = v;
#pragma unroll
    for (int o = 1; o < 64; o <<= 1) {
      const int t = __shfl_up(incl, o, 64);
      if (lane >= o) incl += t;
    }
    if (lane == 63) wsum4[wv] = incl;
  }
  __syncthreads();
  if (tid < hr) {
    int wpre = 0;
    for (int i = 0; i < wv; ++i) wpre += wsum4[i];
    off[tid] = wpre + incl - v;
  }
  __syncthreads();

  // phase 3: scatter my records into LDS CSR (off becomes end offset)
  for (int k = 0; k < nmy; ++k) {
    const unsigned rec = myrec[k];
    const int rl  = (int)(rec >> 17) - rlo;
    const int pos = atomicAdd(&off[rl], 1);
    if (pos < CCAP) cols[pos] = (int)(rec & 0x1FFFFu);
  }
  __syncthreads();

  // phase 4: per-row softmax aggregation, one wave per row (16 waves)
  for (int rl = wv; rl < hr; rl += 16) {
    const int row = row0 + rl;
    if (row >= N_NODES) break;
    const int dcnt  = cnt[rl];
    const int end   = off[rl];
    const int start = end - dcnt;
    const int deg   = min(dcnt, 64);
    const float s1 = s_src[row];

    int c = 0;
    if (lane < deg) c = cols[start + lane];
    float e = s1 + ((lane < deg) ? s_dst[c] : 0.f);
    e = e > 0.f ? e : NEG_SLOPE * e;
    const float ex = __expf(e);

    float acc = 0.f, dsum = 0.f;
    int j = 0;
    for (; j + 4 <= deg; j += 4) {
      const int   c0 = __shfl(c, j, 64),      c1 = __shfl(c, j + 1, 64);
      const int   c2 = __shfl(c, j + 2, 64),  c3 = __shfl(c, j + 3, 64);
      const float e0 = __shfl(ex, j, 64),     e1 = __shfl(ex, j + 1, 64);
      const float e2 = __shfl(ex, j + 2, 64), e3 = __shfl(ex, j + 3, 64);
      const float v0 = bf16u_f(h_lin[(size_t)c0 * OUT_F + lane]);
      const float v1 = bf16u_f(h_lin[(size_t)c1 * OUT_F + lane]);
      const float v2 = bf16u_f(h_lin[(size_t)c2 * OUT_F + lane]);
      const float v3 = bf16u_f(h_lin[(size_t)c3 * OUT_F + lane]);
      acc = fmaf(e0, v0, acc); acc = fmaf(e1, v1, acc);
      acc = fmaf(e2, v2, acc); acc = fmaf(e3, v3, acc);
      dsum += (e0 + e1) + (e2 + e3);
    }
    for (; j < deg; ++j) {
      const int   cj = __shfl(c, j, 64);
      const float ej = __shfl(ex, j, 64);
      acc = fmaf(ej, bf16u_f(h_lin[(size_t)cj * OUT_F + lane]), acc);
      dsum += ej;
    }

    const float hp = acc / dsum;
    out[(size_t)row * OUT_F + lane] = hp > 0.f ? hp : __expf(hp) - 1.f;
  }
}

// ---------------------------------------------------------------------------
extern "C" void kernel_launch(void* const* d_in, const int* in_sizes, int n_in,
                              void* d_out, int out_size, void* d_ws, size_t ws_size,
                              hipStream_t stream) {
  const float* h  = (const float*)d_in[0];
  const float* W  = (const float*)d_in[1];
  const float* a  = (const float*)d_in[2];
  const int*   ei = (const int*)d_in[3];
  float* out = (float*)d_out;

  unsigned short* h_lin = (unsigned short*)d_ws;                 // N*64 bf16
  float* s_src = (float*)(h_lin + (size_t)N_NODES * OUT_F);      // N
  float* s_dst = s_src + N_NODES;                                // N
  int*   gcur  = (int*)(s_dst + N_NODES);                        // NB
  unsigned* regions = (unsigned*)(gcur + NB);                    // NB*GCAP u32

  hipMemsetAsync(gcur, 0, NB * sizeof(int), stream);

  k_linear<<<782, 256, 0, stream>>>(h, W, a, h_lin, s_src, s_dst);

  k_bin<<<(TOTAL_E + TILE - 1) / TILE, 256, 0, stream>>>(ei, gcur, regions);

  // 2 blocks per bucket -> 512 blocks = 2/CU = full 32 waves/CU
  k_agg<<<NB * 2, 1024, 0, stream>>>(h_lin, s_src, s_dst, gcur, regions, out);
}